// Round 1
// 283.096 us; speedup vs baseline: 1.0563x; 1.0563x over previous
//
#include <hip/hip_runtime.h>
#include <math.h>

typedef _Float16 half8   __attribute__((ext_vector_type(8)));
typedef _Float16 half4_t __attribute__((ext_vector_type(4)));
typedef _Float16 half2_t __attribute__((ext_vector_type(2)));
typedef float    floatx4 __attribute__((ext_vector_type(4)));
typedef unsigned int uint4_t __attribute__((ext_vector_type(4)));

namespace {

constexpr int S  = 2048;
constexpr int D  = 64;
constexpr int BH = 32;
constexpr int QT = 64;
constexpr float INV_T = 0.125f;
constexpr size_t PLANE = (size_t)BH * S * D;
constexpr float MBIAS = 2.772588722239781f;   // 4*ln2 (cancels in O/l)

#define MFMA16(a, b, c) __builtin_amdgcn_mfma_f32_16x16x32_f16((a), (b), (c), 0, 0, 0)

typedef __attribute__((address_space(1))) const unsigned int guint;
typedef __attribute__((address_space(3))) unsigned int luint;

__device__ __forceinline__ void gl_lds16(const _Float16* g, _Float16* l) {
    __builtin_amdgcn_global_load_lds((guint*)g, (luint*)l, 16, 0, 0);
}

// pack two f32 -> one dword of two f16 (RTZ)
__device__ __forceinline__ unsigned pk2(float a, float b) {
#if __has_builtin(__builtin_amdgcn_cvt_pkrtz)
    auto h = __builtin_amdgcn_cvt_pkrtz(a, b);
    return __builtin_bit_cast(unsigned, h);
#else
    half2_t h = {(_Float16)a, (_Float16)b};
    return __builtin_bit_cast(unsigned, h);
#endif
}

// v_permlane32_swap_b32: a[32+i] <-> b[i]  (i=0..31)
__device__ __forceinline__ void pl32swap(unsigned &a, unsigned &b) {
    asm("v_permlane32_swap_b32 %0, %1" : "+v"(a), "+v"(b));
}
// v_permlane16_swap_b32: a[16+i] <-> b[i] within each 32-lane half
__device__ __forceinline__ void pl16swap(unsigned &a, unsigned &b) {
    asm("v_permlane16_swap_b32 %0, %1" : "+v"(a), "+v"(b));
}

// In-register 16x32 P transpose across the g-quad {m, m+16, m+32, m+48}.
// Inputs: A0=pk(t=4g,4g+1) A1=pk(4g+2,4g+3) of nt0; B0,B1 same of nt1 (t+16).
// Output: half8 A-fragment = t in [8g, 8g+8) at q=m.
__device__ __forceinline__ half8 xpose4(unsigned A0, unsigned A1,
                                        unsigned B0, unsigned B1) {
    pl32swap(A0, B0);            // A0 -> X0, B0 -> Y0
    pl32swap(A1, B1);
    pl16swap(A0, B0);            // X0,Y0 -> D0,D2
    pl16swap(A1, B1);            // X1,Y1 -> D1,D3
    uint4_t d = (uint4_t){A0, A1, B0, B1};
    return __builtin_bit_cast(half8, d);
}

// ---- fused pre-pass: K -> f16 swizzled [bh][t][d] (key t&7, 8-chunk rows);
// ----                 V -> f16 transposed [bh][d][s], swizzle within 32-half windows (key d&3)
__global__ __launch_bounds__(256)
void prep_all(const float* __restrict__ kr, const float* __restrict__ ki,
              const float* __restrict__ vr, const float* __restrict__ vi,
              _Float16* __restrict__ okr, _Float16* __restrict__ oki,
              _Float16* __restrict__ ovr, _Float16* __restrict__ ovi)
{
    __shared__ _Float16 tile[64][72];
    const int z  = (int)blockIdx.z;
    const int bh = (int)blockIdx.y, t0 = (int)blockIdx.x * 64;
    const int tid = (int)threadIdx.x;

    if (z < 2) {
        const float* src = z ? ki : kr;
        _Float16*    dst = z ? oki : okr;
        const int r = tid >> 2, cg = tid & 3;
        const size_t in = ((size_t)bh * S + t0 + r) * D + cg * 16;
        float4 f0 = *(const float4*)(src + in);
        float4 f1 = *(const float4*)(src + in + 4);
        float4 f2 = *(const float4*)(src + in + 8);
        float4 f3 = *(const float4*)(src + in + 12);
        half8 h0, h1;
        h0[0]=(_Float16)f0.x; h0[1]=(_Float16)f0.y; h0[2]=(_Float16)f0.z; h0[3]=(_Float16)f0.w;
        h0[4]=(_Float16)f1.x; h0[5]=(_Float16)f1.y; h0[6]=(_Float16)f1.z; h0[7]=(_Float16)f1.w;
        h1[0]=(_Float16)f2.x; h1[1]=(_Float16)f2.y; h1[2]=(_Float16)f2.z; h1[3]=(_Float16)f2.w;
        h1[4]=(_Float16)f3.x; h1[5]=(_Float16)f3.y; h1[6]=(_Float16)f3.z; h1[7]=(_Float16)f3.w;
        const int key = r & 7;
        const size_t ob = ((size_t)bh * S + t0 + r) * D;
        *(half8*)(dst + ob + ((cg*2    ) ^ key) * 8) = h0;
        *(half8*)(dst + ob + ((cg*2 + 1) ^ key) * 8) = h1;
    } else {
        const float* src = (z == 3) ? vi : vr;
        _Float16*    dst = (z == 3) ? ovi : ovr;
        const int r = tid & 63, cg = tid >> 6;   // wave = col-group: conflict-free LDS writes
        const size_t in = ((size_t)bh * S + t0 + r) * D + cg * 16;
        #pragma unroll
        for (int j = 0; j < 4; ++j) {
            float4 f = *(const float4*)(src + in + j * 4);
            tile[cg*16 + j*4 + 0][r] = (_Float16)f.x;
            tile[cg*16 + j*4 + 1][r] = (_Float16)f.y;
            tile[cg*16 + j*4 + 2][r] = (_Float16)f.z;
            tile[cg*16 + j*4 + 3][r] = (_Float16)f.w;
        }
        __syncthreads();
        const int d = tid >> 2, c2 = tid & 3;
        const int key = d & 3;                    // swizzle within 32-half (4-chunk) windows
        const size_t ob = ((size_t)bh * D + d) * S + t0;
        half8 a = *(const half8*)&tile[d][c2*16];
        half8 b = *(const half8*)&tile[d][c2*16 + 8];
        const int j0 = c2*2, j1 = c2*2 + 1;
        *(half8*)(dst + ob + (size_t)(((j0 & 4) | ((j0 & 3) ^ key))) * 8) = a;
        *(half8*)(dst + ob + (size_t)(((j1 & 4) | ((j1 & 3) ^ key))) * 8) = b;
    }
}

// ---- main: 16x16x32 MFMA flash complex attention, KT=32 double-buffered ----
// Swapped QK^T (Z^T = mfma(K,Q)) makes q lane-local; P transpose done fully
// in-register via permlane swaps -> no P LDS buffer, no bank conflicts.
__global__ __launch_bounds__(256, 4)
void cv_attn_db(const float* __restrict__ qr_g, const float* __restrict__ qi_g,
                const _Float16* __restrict__ kh_r, const _Float16* __restrict__ kh_i,
                const _Float16* __restrict__ vt_r, const _Float16* __restrict__ vt_i,
                float* __restrict__ out)
{
    // 2 bufs x 4 planes x 2048 halves = 32768 B -> 4 blocks/CU (grid-limited)
    __shared__ __align__(16) _Float16 sm[2*4*2048];

    const int tid = (int)threadIdx.x, lane = tid & 63, wv = tid >> 6;
    const int g = lane >> 4, m = lane & 15;

    // XCD-aware decode: one bh per XCD slice (f16 K/V ~1MB/bh stays L2-local)
    const int b   = (int)blockIdx.x;
    const int xcd = b & 7, y = b >> 3;
    const int qt  = y & 31, bh = xcd + 8 * (y >> 5);
    const int q0  = qt * QT;
    const size_t base = (size_t)bh * S * D;

    // ---- Q fragments (row=m, k=g*8+j + kc*32), scaled by 1/T; Qi negated once ----
    half8 aqr[2], aqi[2], aqin[2];
    {
        const size_t qoff = base + (size_t)(q0 + wv*16 + m) * D + g*8;
        #pragma unroll
        for (int kc = 0; kc < 2; ++kc) {
            float4 r0 = *(const float4*)(qr_g + qoff + kc*32);
            float4 r1 = *(const float4*)(qr_g + qoff + kc*32 + 4);
            float4 i0 = *(const float4*)(qi_g + qoff + kc*32);
            float4 i1 = *(const float4*)(qi_g + qoff + kc*32 + 4);
            half8 hr, hi;
            hr[0]=(_Float16)(r0.x*INV_T); hr[1]=(_Float16)(r0.y*INV_T);
            hr[2]=(_Float16)(r0.z*INV_T); hr[3]=(_Float16)(r0.w*INV_T);
            hr[4]=(_Float16)(r1.x*INV_T); hr[5]=(_Float16)(r1.y*INV_T);
            hr[6]=(_Float16)(r1.z*INV_T); hr[7]=(_Float16)(r1.w*INV_T);
            hi[0]=(_Float16)(i0.x*INV_T); hi[1]=(_Float16)(i0.y*INV_T);
            hi[2]=(_Float16)(i0.z*INV_T); hi[3]=(_Float16)(i0.w*INV_T);
            hi[4]=(_Float16)(i1.x*INV_T); hi[5]=(_Float16)(i1.y*INV_T);
            hi[6]=(_Float16)(i1.z*INV_T); hi[7]=(_Float16)(i1.w*INV_T);
            aqr[kc] = hr; aqi[kc] = hi; aqin[kc] = -hi;
        }
    }

    floatx4 Or[4], Oi[4];
    float l_run = 0.f;                       // l for q=m (lane-local under swapped QK^T)
    #pragma unroll
    for (int nt = 0; nt < 4; ++nt) {
        Or[nt] = (floatx4){0.f,0.f,0.f,0.f};
        Oi[nt] = (floatx4){0.f,0.f,0.f,0.f};
    }

    // stage tile kt (32 keys) into buffer bs: wave w stages one plane verbatim (pre-swizzled)
    auto stage = [&](int kt, _Float16* bs) {
        const int k0 = kt * 32;
        if (wv < 2) {
            const _Float16* src = (wv ? kh_i : kh_r) + ((size_t)bh*S + k0)*D + lane*8;
            _Float16* dst = bs + wv*2048;
            #pragma unroll
            for (int i = 0; i < 4; ++i)
                gl_lds16(src + i*512, dst + i*512);
        } else {
            const _Float16* src = (wv == 2 ? vt_r : vt_i)
                                + ((size_t)bh*D + (lane>>2))*S + k0 + (lane&3)*8;
            _Float16* dst = bs + wv*2048;
            #pragma unroll
            for (int i = 0; i < 4; ++i)
                gl_lds16(src + (size_t)i*16*S, dst + i*512);
        }
    };

    auto compute = [&](const _Float16* bs) {
        const _Float16* const Krt = bs;
        const _Float16* const Kit = bs + 2048;
        const _Float16* const Vrt = bs + 4096;
        const _Float16* const Vit = bs + 6144;

        // ---- scores, swapped: Z^T block nt -> lane holds t = 16nt+4g+r, q = m ----
        floatx4 Zr[2], Zi[2];
        #pragma unroll
        for (int nt = 0; nt < 2; ++nt) {
            const int rb  = (nt*16 + m) * 64;
            const int key = m & 7;
            const int ck0 = (g ^ key) * 8, ck1 = ((g + 4) ^ key) * 8;
            half8 bkr0 = *(const half8*)&Krt[rb + ck0];
            half8 bki0 = *(const half8*)&Kit[rb + ck0];
            half8 bkr1 = *(const half8*)&Krt[rb + ck1];
            half8 bki1 = *(const half8*)&Kit[rb + ck1];
            floatx4 zr = (floatx4){0.f,0.f,0.f,0.f};
            floatx4 zi = (floatx4){0.f,0.f,0.f,0.f};
            zr = MFMA16(bkr0, aqr[0],  zr);
            zr = MFMA16(bki0, aqin[0], zr);
            zr = MFMA16(bkr1, aqr[1],  zr);
            zr = MFMA16(bki1, aqin[1], zr);    // Zr^T = Kr Qr' - Ki Qi'
            zi = MFMA16(bki0, aqr[0],  zi);
            zi = MFMA16(bkr0, aqi[0],  zi);
            zi = MFMA16(bki1, aqr[1],  zi);
            zi = MFMA16(bkr1, aqi[1],  zi);    // Zi^T = Ki Qr' + Kr Qi'
            Zr[nt] = zr; Zi[nt] = zi;
        }

        // ---- max-free softmax in-register: p = exp(|z|)*2^-4; P = p*z/|z| ----
        unsigned PkR[4], PkI[4];   // chunk c = nt*2 + pair: pk(t pair) at group g
        #pragma unroll
        for (int nt = 0; nt < 2; ++nt) {
            float wr[4], wi[4];
            #pragma unroll
            for (int r = 0; r < 4; ++r) {
                const float zr = Zr[nt][r], zi = Zi[nt][r];
                const float s2  = fmaf(zr, zr, fmaf(zi, zi, 1e-24f));
                const float inv = __builtin_amdgcn_rsqf(s2);
                const float mag = s2 * inv;
                const float p   = __expf(mag - MBIAS);
                l_run += p;
                const float w = p * inv;
                wr[r] = w * zr; wi[r] = w * zi;
            }
            PkR[nt*2 + 0] = pk2(wr[0], wr[1]);
            PkR[nt*2 + 1] = pk2(wr[2], wr[3]);
            PkI[nt*2 + 0] = pk2(wi[0], wi[1]);
            PkI[nt*2 + 1] = pk2(wi[2], wi[3]);
        }

        // ---- in-register P transpose: A-fragment (q=m, t=8g..8g+7) per plane ----
        half8 apr = xpose4(PkR[0], PkR[1], PkR[2], PkR[3]);
        half8 api = xpose4(PkI[0], PkI[1], PkI[2], PkI[3]);
        half8 nai = -api;

        // ---- PV: O += P * V (B = Vt rows = d, 32-half windows) ----
        #pragma unroll
        for (int nt = 0; nt < 4; ++nt) {
            const int vrb = (nt*16 + m) * 32;
            const int vck = (g ^ (m & 3)) * 8;
            half8 bvr = *(const half8*)&Vrt[vrb + vck];
            half8 bvi = *(const half8*)&Vit[vrb + vck];
            Or[nt] = MFMA16(apr, bvr, Or[nt]);
            Or[nt] = MFMA16(nai, bvi, Or[nt]);
            Oi[nt] = MFMA16(apr, bvi, Oi[nt]);
            Oi[nt] = MFMA16(api, bvr, Oi[nt]);
        }
    };

    _Float16* const buf0 = sm;
    _Float16* const buf1 = sm + 4*2048;

    stage(0, buf0);
    for (int kt = 0; kt < 64; kt += 2) {
        __syncthreads();                    // drains loads into buf0; separates prior compute(buf1)
        stage(kt + 1, buf1);
        compute(buf0);
        __syncthreads();                    // drains loads into buf1; separates compute(buf0)
        if (kt < 62) stage(kt + 2, buf0);
        compute(buf1);
    }

    // ---- deferred l reduction: sum over the g-quad (each lane has 8 t's per tile) ----
    l_run += __shfl_xor(l_run, 16, 64);
    l_run += __shfl_xor(l_run, 32, 64);
    // lane quad {m,m+16,m+32,m+48} now holds l(q=m); gather l(q=4g+r) for output rows

    #pragma unroll
    for (int r = 0; r < 4; ++r) {
        const float linv = 1.0f / __shfl(l_run, 4*g + r, 64);
        const size_t o = base + (size_t)(q0 + wv*16 + 4*g + r) * D + m;
        #pragma unroll
        for (int nt = 0; nt < 4; ++nt) {
            out[o + nt*16]         = Or[nt][r] * linv;
            out[PLANE + o + nt*16] = Oi[nt][r] * linv;
        }
    }
}

// ---------------- fallback (ws too small): round-2 style, f32 inputs ----------------
constexpr int ST2 = 72;
__global__ __launch_bounds__(256, 2)
void cv_attn_mfma(const float* __restrict__ qr_g, const float* __restrict__ qi_g,
                  const float* __restrict__ kr_g, const float* __restrict__ ki_g,
                  const float* __restrict__ vr_g, const float* __restrict__ vi_g,
                  float* __restrict__ out)
{
    __shared__ __align__(16) _Float16 sm[4*64*ST2 + 4*2*16*ST2];
    _Float16* const Kr = sm;
    _Float16* const Ki = Kr + 64*ST2;
    _Float16* const Vr = Ki + 64*ST2;
    _Float16* const Vi = Vr + 64*ST2;
    _Float16* const Pb = Vi + 64*ST2;

    const int tid = (int)threadIdx.x, lane = tid & 63, wv = tid >> 6;
    const int g = lane >> 4, m = lane & 15;
    const int bh = (int)blockIdx.y;
    const int q0 = (int)blockIdx.x * QT;
    const size_t base = (size_t)bh * S * D;
    _Float16* const Pr = Pb + wv * (2*16*ST2);
    _Float16* const Pi = Pr + 16*ST2;
    const int lofs = m*ST2 + g*8;

    half8 aqr[2], aqi[2], aqin[2];
    {
        const size_t qoff = base + (size_t)(q0 + wv*16 + m) * D + g*8;
        #pragma unroll
        for (int kc = 0; kc < 2; ++kc) {
            float4 r0 = *(const float4*)(qr_g + qoff + kc*32);
            float4 r1 = *(const float4*)(qr_g + qoff + kc*32 + 4);
            float4 i0 = *(const float4*)(qi_g + qoff + kc*32);
            float4 i1 = *(const float4*)(qi_g + qoff + kc*32 + 4);
            half8 hr, hi;
            hr[0]=(_Float16)(r0.x*INV_T); hr[1]=(_Float16)(r0.y*INV_T);
            hr[2]=(_Float16)(r0.z*INV_T); hr[3]=(_Float16)(r0.w*INV_T);
            hr[4]=(_Float16)(r1.x*INV_T); hr[5]=(_Float16)(r1.y*INV_T);
            hr[6]=(_Float16)(r1.z*INV_T); hr[7]=(_Float16)(r1.w*INV_T);
            hi[0]=(_Float16)(i0.x*INV_T); hi[1]=(_Float16)(i0.y*INV_T);
            hi[2]=(_Float16)(i0.z*INV_T); hi[3]=(_Float16)(i0.w*INV_T);
            hi[4]=(_Float16)(i1.x*INV_T); hi[5]=(_Float16)(i1.y*INV_T);
            hi[6]=(_Float16)(i1.z*INV_T); hi[7]=(_Float16)(i1.w*INV_T);
            aqr[kc] = hr; aqi[kc] = hi; aqin[kc] = -hi;
        }
    }

    floatx4 Or[4], Oi[4];
    float m_run[4], l_run[4];
    #pragma unroll
    for (int r = 0; r < 4; ++r) { m_run[r] = -INFINITY; l_run[r] = 0.f; }
    #pragma unroll
    for (int nt = 0; nt < 4; ++nt) {
        Or[nt] = (floatx4){0.f,0.f,0.f,0.f};
        Oi[nt] = (floatx4){0.f,0.f,0.f,0.f};
    }

    for (int kt = 0; kt < S/64; ++kt) {
        const int k0 = kt * 64;
        __syncthreads();
        if (wv < 2) {
            const float* src = (wv == 0 ? kr_g : ki_g) + base + (size_t)k0 * D;
            _Float16* dst = (wv == 0 ? Kr : Ki);
            #pragma unroll
            for (int it = 0; it < 16; ++it) {
                const int e = it*64 + lane, t = e >> 4, c4 = (e & 15) * 4;
                float4 v = *(const float4*)(src + t*64 + c4);
                half4_t hh = {(_Float16)v.x, (_Float16)v.y, (_Float16)v.z, (_Float16)v.w};
                *(half4_t*)&dst[t*ST2 + c4] = hh;
            }
        } else {
            const float* src = (wv == 2 ? vr_g : vi_g) + base + (size_t)k0 * D;
            _Float16* dst = (wv == 2 ? Vr : Vi);
            #pragma unroll
            for (int t0 = 0; t0 < 64; t0 += 4) {
                float v0 = src[(t0+0)*64 + lane];
                float v1 = src[(t0+1)*64 + lane];
                float v2 = src[(t0+2)*64 + lane];
                float v3 = src[(t0+3)*64 + lane];
                half4_t hh = {(_Float16)v0, (_Float16)v1, (_Float16)v2, (_Float16)v3};
                *(half4_t*)&dst[lane*ST2 + t0] = hh;
            }
        }
        __syncthreads();

        floatx4 Zr[4], Zi[4];
        #pragma unroll
        for (int nt = 0; nt < 4; ++nt) {
            floatx4 zr = (floatx4){0.f,0.f,0.f,0.f};
            floatx4 zi = (floatx4){0.f,0.f,0.f,0.f};
            #pragma unroll
            for (int kc = 0; kc < 2; ++kc) {
                const int o = nt*16*ST2 + lofs + kc*32;
                half8 bkr = *(const half8*)&Kr[o];
                half8 bki = *(const half8*)&Ki[o];
                zr = MFMA16(aqr[kc],  bkr, zr);
                zr = MFMA16(aqin[kc], bki, zr);
                zi = MFMA16(aqr[kc],  bki, zi);
                zi = MFMA16(aqi[kc],  bkr, zi);
            }
            Zr[nt] = zr; Zi[nt] = zi;
        }

        float mag[4][4], mt[4] = {0.f,0.f,0.f,0.f};
        #pragma unroll
        for (int nt = 0; nt < 4; ++nt)
            #pragma unroll
            for (int r = 0; r < 4; ++r) {
                const float a = Zr[nt][r], bz = Zi[nt][r];
                const float s = __builtin_amdgcn_sqrtf(a*a + bz*bz);
                mag[nt][r] = s; mt[r] = fmaxf(mt[r], s);
            }
        #pragma unroll
        for (int off = 1; off < 16; off <<= 1)
            #pragma unroll
            for (int r = 0; r < 4; ++r)
                mt[r] = fmaxf(mt[r], __shfl_xor(mt[r], off, 64));

        float alpha[4], rs[4];
        #pragma unroll
        for (int r = 0; r < 4; ++r) {
            const float mnew = fmaxf(m_run[r], mt[r]);
            alpha[r] = __expf(m_run[r] - mnew);
            m_run[r] = mnew; rs[r] = 0.f;
        }
        #pragma unroll
        for (int nt = 0; nt < 4; ++nt)
            #pragma unroll
            for (int r = 0; r < 4; ++r) {
                const float p = __expf(mag[nt][r] - m_run[r]);
                rs[r] += p;
                const float w = p * __builtin_amdgcn_rcpf(fmaxf(mag[nt][r], 1e-12f));
                Pr[(4*g + r)*ST2 + nt*16 + m] = (_Float16)(w * Zr[nt][r]);
                Pi[(4*g + r)*ST2 + nt*16 + m] = (_Float16)(w * Zi[nt][r]);
            }
        #pragma unroll
        for (int off = 1; off < 16; off <<= 1)
            #pragma unroll
            for (int r = 0; r < 4; ++r)
                rs[r] += __shfl_xor(rs[r], off, 64);
        #pragma unroll
        for (int r = 0; r < 4; ++r) l_run[r] = l_run[r]*alpha[r] + rs[r];

        #pragma unroll
        for (int nt = 0; nt < 4; ++nt)
            #pragma unroll
            for (int r = 0; r < 4; ++r) { Or[nt][r] *= alpha[r]; Oi[nt][r] *= alpha[r]; }

        half8 apr[2], api[2], apin[2];
        #pragma unroll
        for (int kc = 0; kc < 2; ++kc) {
            apr[kc]  = *(const half8*)&Pr[lofs + kc*32];
            api[kc]  = *(const half8*)&Pi[lofs + kc*32];
            apin[kc] = -api[kc];
        }
        #pragma unroll
        for (int nt = 0; nt < 4; ++nt) {
            floatx4 ors = Or[nt], ois = Oi[nt];
            #pragma unroll
            for (int kc = 0; kc < 2; ++kc) {
                const int o = nt*16*ST2 + lofs + kc*32;
                half8 bvr = *(const half8*)&Vr[o];
                half8 bvi = *(const half8*)&Vi[o];
                ors = MFMA16(apr[kc],  bvr, ors);
                ors = MFMA16(apin[kc], bvi, ors);
                ois = MFMA16(apr[kc],  bvi, ois);
                ois = MFMA16(api[kc],  bvr, ois);
            }
            Or[nt] = ors; Oi[nt] = ois;
        }
    }

    #pragma unroll
    for (int r = 0; r < 4; ++r) {
        const float linv = 1.0f / l_run[r];
        const size_t o = base + (size_t)(q0 + wv*16 + 4*g + r) * D + m;
        #pragma unroll
        for (int nt = 0; nt < 4; ++nt) {
            out[o + nt*16]         = Or[nt][r] * linv;
            out[PLANE + o + nt*16] = Oi[nt][r] * linv;
        }
    }
}

} // namespace

extern "C" void kernel_launch(void* const* d_in, const int* in_sizes, int n_in,
                              void* d_out, int out_size, void* d_ws, size_t ws_size,
                              hipStream_t stream) {
    const float* qr = (const float*)d_in[0];
    const float* qi = (const float*)d_in[1];
    const float* kr = (const float*)d_in[2];
    const float* ki = (const float*)d_in[3];
    const float* vr = (const float*)d_in[4];
    const float* vi = (const float*)d_in[5];
    float* out = (float*)d_out;

    const size_t PH = (size_t)BH * S * D;            // halves per ws plane
    const size_t need = 4 * PH * sizeof(_Float16);   // 33.6 MB
    if (ws_size >= need) {
        _Float16* khr = (_Float16*)d_ws;
        _Float16* khi = khr + PH;
        _Float16* vtr = khi + PH;
        _Float16* vti = vtr + PH;
        prep_all<<<dim3(32, 32, 4), 256, 0, stream>>>(kr, ki, vr, vi, khr, khi, vtr, vti);
        cv_attn_db<<<1024, 256, 0, stream>>>(qr, qi, khr, khi, vtr, vti, out);
    } else {
        cv_attn_mfma<<<dim3(32, 32), 256, 0, stream>>>(qr, qi, kr, ki, vr, vi, out);
    }
}

// Round 4
// 280.055 us; speedup vs baseline: 1.0677x; 1.0109x over previous
//
#include <hip/hip_runtime.h>
#include <math.h>

typedef _Float16 half8   __attribute__((ext_vector_type(8)));
typedef _Float16 half4_t __attribute__((ext_vector_type(4)));
typedef _Float16 half2_t __attribute__((ext_vector_type(2)));
typedef float    floatx4 __attribute__((ext_vector_type(4)));
typedef unsigned int uint4_t __attribute__((ext_vector_type(4)));

namespace {

constexpr int S  = 2048;
constexpr int D  = 64;
constexpr int BH = 32;
constexpr int QT = 64;
constexpr float INV_T = 0.125f;
constexpr size_t PLANE = (size_t)BH * S * D;
constexpr float MBIAS = 2.772588722239781f;   // 4*ln2 (cancels in O/l)

#define MFMA16(a, b, c) __builtin_amdgcn_mfma_f32_16x16x32_f16((a), (b), (c), 0, 0, 0)

typedef __attribute__((address_space(1))) const unsigned int guint;
typedef __attribute__((address_space(3))) unsigned int luint;

__device__ __forceinline__ void gl_lds16(const _Float16* g, _Float16* l) {
    __builtin_amdgcn_global_load_lds((guint*)g, (luint*)l, 16, 0, 0);
}

// pack two f32 -> one dword of two f16 (RTZ)
__device__ __forceinline__ unsigned pk2(float a, float b) {
#if __has_builtin(__builtin_amdgcn_cvt_pkrtz)
    auto h = __builtin_amdgcn_cvt_pkrtz(a, b);
    return __builtin_bit_cast(unsigned, h);
#else
    half2_t h = {(_Float16)a, (_Float16)b};
    return __builtin_bit_cast(unsigned, h);
#endif
}

// v_permlane32_swap_b32: a[32+i] <-> b[i]  (i=0..31)
__device__ __forceinline__ void pl32swap(unsigned &a, unsigned &b) {
    asm("v_permlane32_swap_b32 %0, %1" : "+v"(a), "+v"(b));
}
// v_permlane16_swap_b32: a[16+i] <-> b[i] within each 32-lane half
__device__ __forceinline__ void pl16swap(unsigned &a, unsigned &b) {
    asm("v_permlane16_swap_b32 %0, %1" : "+v"(a), "+v"(b));
}

// In-register 16x32 P transpose across the g-quad {m, m+16, m+32, m+48}.
// Inputs: A0=pk(t=4g,4g+1) A1=pk(4g+2,4g+3) of nt0; B0,B1 same of nt1 (t+16).
// Output: half8 A-fragment = t in [8g, 8g+8) at q=m.
__device__ __forceinline__ half8 xpose4(unsigned A0, unsigned A1,
                                        unsigned B0, unsigned B1) {
    pl32swap(A0, B0);            // A0 -> X0, B0 -> Y0
    pl32swap(A1, B1);
    pl16swap(A0, B0);            // X0,Y0 -> D0,D2
    pl16swap(A1, B1);            // X1,Y1 -> D1,D3
    uint4_t d = (uint4_t){A0, A1, B0, B1};
    return __builtin_bit_cast(half8, d);
}

// ---- fused pre-pass: K -> f16 swizzled [bh][t][d] (key t&7, 8-chunk rows);
// ----                 V -> f16 transposed [bh][d][s], swizzle within 32-half windows (key d&3)
// ---- (identical to the verified R1 kernel)
__global__ __launch_bounds__(256)
void prep_all(const float* __restrict__ kr, const float* __restrict__ ki,
              const float* __restrict__ vr, const float* __restrict__ vi,
              _Float16* __restrict__ okr, _Float16* __restrict__ oki,
              _Float16* __restrict__ ovr, _Float16* __restrict__ ovi)
{
    __shared__ _Float16 tile[64][72];
    const int z  = (int)blockIdx.z;
    const int bh = (int)blockIdx.y, t0 = (int)blockIdx.x * 64;
    const int tid = (int)threadIdx.x;

    if (z < 2) {
        const float* src = z ? ki : kr;
        _Float16*    dst = z ? oki : okr;
        const int r = tid >> 2, cg = tid & 3;
        const size_t in = ((size_t)bh * S + t0 + r) * D + cg * 16;
        float4 f0 = *(const float4*)(src + in);
        float4 f1 = *(const float4*)(src + in + 4);
        float4 f2 = *(const float4*)(src + in + 8);
        float4 f3 = *(const float4*)(src + in + 12);
        half8 h0, h1;
        h0[0]=(_Float16)f0.x; h0[1]=(_Float16)f0.y; h0[2]=(_Float16)f0.z; h0[3]=(_Float16)f0.w;
        h0[4]=(_Float16)f1.x; h0[5]=(_Float16)f1.y; h0[6]=(_Float16)f1.z; h0[7]=(_Float16)f1.w;
        h1[0]=(_Float16)f2.x; h1[1]=(_Float16)f2.y; h1[2]=(_Float16)f2.z; h1[3]=(_Float16)f2.w;
        h1[4]=(_Float16)f3.x; h1[5]=(_Float16)f3.y; h1[6]=(_Float16)f3.z; h1[7]=(_Float16)f3.w;
        const int key = r & 7;
        const size_t ob = ((size_t)bh * S + t0 + r) * D;
        *(half8*)(dst + ob + ((cg*2    ) ^ key) * 8) = h0;
        *(half8*)(dst + ob + ((cg*2 + 1) ^ key) * 8) = h1;
    } else {
        const float* src = (z == 3) ? vi : vr;
        _Float16*    dst = (z == 3) ? ovi : ovr;
        const int r = tid & 63, cg = tid >> 6;   // wave = col-group: conflict-free LDS writes
        const size_t in = ((size_t)bh * S + t0 + r) * D + cg * 16;
        #pragma unroll
        for (int j = 0; j < 4; ++j) {
            float4 f = *(const float4*)(src + in + j * 4);
            tile[cg*16 + j*4 + 0][r] = (_Float16)f.x;
            tile[cg*16 + j*4 + 1][r] = (_Float16)f.y;
            tile[cg*16 + j*4 + 2][r] = (_Float16)f.z;
            tile[cg*16 + j*4 + 3][r] = (_Float16)f.w;
        }
        __syncthreads();
        const int d = tid >> 2, c2 = tid & 3;
        const int key = d & 3;                    // swizzle within 32-half (4-chunk) windows
        const size_t ob = ((size_t)bh * D + d) * S + t0;
        half8 a = *(const half8*)&tile[d][c2*16];
        half8 b = *(const half8*)&tile[d][c2*16 + 8];
        const int j0 = c2*2, j1 = c2*2 + 1;
        *(half8*)(dst + ob + (size_t)(((j0 & 4) | ((j0 & 3) ^ key))) * 8) = a;
        *(half8*)(dst + ob + (size_t)(((j1 & 4) | ((j1 & 3) ^ key))) * 8) = b;
    }
}

// ---- main: 16x16x32 MFMA flash complex attention, KT=32 double-buffered ----
// Swapped QK^T (Z^T = mfma(K,Q)) makes q lane-local; P transpose fully
// in-register via permlane swaps. V rows are placed at permuted LDS slots
// (phi = swap bit0<->bit2 of m) so the PV ds_read_b128 phase hits all 8
// bank-quads (2-per-quad floor); data routing is byte-identical to R1.
__global__ __launch_bounds__(256, 4)
void cv_attn_db(const float* __restrict__ qr_g, const float* __restrict__ qi_g,
                const _Float16* __restrict__ kh_r, const _Float16* __restrict__ kh_i,
                const _Float16* __restrict__ vt_r, const _Float16* __restrict__ vt_i,
                float* __restrict__ out)
{
    // 2 bufs x 4 planes x 2048 halves = 32768 B
    __shared__ __align__(16) _Float16 sm[2*4*2048];

    const int tid = (int)threadIdx.x, lane = tid & 63, wv = tid >> 6;
    const int g = lane >> 4, m = lane & 15;
    // phi(m): swap bit0 <-> bit2 (involution). Used for V row slot placement.
    const int fm = (m & 10) | ((m & 1) << 2) | ((m >> 2) & 1);

    // XCD-aware decode: one bh per XCD slice (f16 K/V ~1MB/bh stays L2-local)
    const int b   = (int)blockIdx.x;
    const int xcd = b & 7, y = b >> 3;
    const int qt  = y & 31, bh = xcd + 8 * (y >> 5);
    const int q0  = qt * QT;
    const size_t base = (size_t)bh * S * D;

    // ---- Q fragments (row=m, k=g*8+j + kc*32), scaled by 1/T; Qi negated once ----
    half8 aqr[2], aqi[2], aqin[2];
    {
        const size_t qoff = base + (size_t)(q0 + wv*16 + m) * D + g*8;
        #pragma unroll
        for (int kc = 0; kc < 2; ++kc) {
            float4 r0 = *(const float4*)(qr_g + qoff + kc*32);
            float4 r1 = *(const float4*)(qr_g + qoff + kc*32 + 4);
            float4 i0 = *(const float4*)(qi_g + qoff + kc*32);
            float4 i1 = *(const float4*)(qi_g + qoff + kc*32 + 4);
            half8 hr, hi;
            hr[0]=(_Float16)(r0.x*INV_T); hr[1]=(_Float16)(r0.y*INV_T);
            hr[2]=(_Float16)(r0.z*INV_T); hr[3]=(_Float16)(r0.w*INV_T);
            hr[4]=(_Float16)(r1.x*INV_T); hr[5]=(_Float16)(r1.y*INV_T);
            hr[6]=(_Float16)(r1.z*INV_T); hr[7]=(_Float16)(r1.w*INV_T);
            hi[0]=(_Float16)(i0.x*INV_T); hi[1]=(_Float16)(i0.y*INV_T);
            hi[2]=(_Float16)(i0.z*INV_T); hi[3]=(_Float16)(i0.w*INV_T);
            hi[4]=(_Float16)(i1.x*INV_T); hi[5]=(_Float16)(i1.y*INV_T);
            hi[6]=(_Float16)(i1.z*INV_T); hi[7]=(_Float16)(i1.w*INV_T);
            aqr[kc] = hr; aqi[kc] = hi; aqin[kc] = -hi;
        }
    }

    floatx4 Or[4], Oi[4];
    float l_run = 0.f;                       // l for q=m (lane-local under swapped QK^T)
    #pragma unroll
    for (int nt = 0; nt < 4; ++nt) {
        Or[nt] = (floatx4){0.f,0.f,0.f,0.f};
        Oi[nt] = (floatx4){0.f,0.f,0.f,0.f};
    }

    // stage tile kt (32 keys) into buffer bs. K planes verbatim; V planes with
    // phi-permuted row slots: LDS slot (lane>>2)+i*16 holds global row
    // phi(lane>>2)+i*16 (per-lane global addr; LDS dest stays linear).
    auto stage = [&](int kt, _Float16* bs) {
        const int k0 = kt * 32;
        if (wv < 2) {
            const _Float16* src = (wv ? kh_i : kh_r) + ((size_t)bh*S + k0)*D + lane*8;
            _Float16* dst = bs + wv*2048;
            #pragma unroll
            for (int i = 0; i < 4; ++i)
                gl_lds16(src + i*512, dst + i*512);
        } else {
            const int dl  = lane >> 2;
            const int fdl = (dl & 10) | ((dl & 1) << 2) | ((dl >> 2) & 1);  // phi
            const _Float16* src = (wv == 2 ? vt_r : vt_i)
                                + ((size_t)bh*D + fdl)*S + k0 + (lane&3)*8;
            _Float16* dst = bs + wv*2048;
            #pragma unroll
            for (int i = 0; i < 4; ++i)
                gl_lds16(src + (size_t)i*16*S, dst + i*512);
        }
    };

    auto compute = [&](const _Float16* bs) {
        const _Float16* const Krt = bs;
        const _Float16* const Kit = bs + 2048;
        const _Float16* const Vrt = bs + 4096;
        const _Float16* const Vit = bs + 6144;

        // ---- scores, swapped: Z^T block nt -> lane holds t = 16nt+4g+r, q = m ----
        floatx4 Zr[2], Zi[2];
        #pragma unroll
        for (int nt = 0; nt < 2; ++nt) {
            const int rb  = (nt*16 + m) * 64;
            const int key = m & 7;
            const int ck0 = (g ^ key) * 8, ck1 = ((g + 4) ^ key) * 8;
            half8 bkr0 = *(const half8*)&Krt[rb + ck0];
            half8 bki0 = *(const half8*)&Kit[rb + ck0];
            half8 bkr1 = *(const half8*)&Krt[rb + ck1];
            half8 bki1 = *(const half8*)&Kit[rb + ck1];
            floatx4 zr = (floatx4){0.f,0.f,0.f,0.f};
            floatx4 zi = (floatx4){0.f,0.f,0.f,0.f};
            zr = MFMA16(bkr0, aqr[0],  zr);
            zr = MFMA16(bki0, aqin[0], zr);
            zr = MFMA16(bkr1, aqr[1],  zr);
            zr = MFMA16(bki1, aqin[1], zr);    // Zr^T = Kr Qr' - Ki Qi'
            zi = MFMA16(bki0, aqr[0],  zi);
            zi = MFMA16(bkr0, aqi[0],  zi);
            zi = MFMA16(bki1, aqr[1],  zi);
            zi = MFMA16(bkr1, aqi[1],  zi);    // Zi^T = Ki Qr' + Kr Qi'
            Zr[nt] = zr; Zi[nt] = zi;
        }

        // ---- max-free softmax: p = exp(|z|)*2^-4; P = p*z/|z| (in-register) ----
        unsigned PkR[4], PkI[4];   // chunk c = nt*2 + pair: pk(t pair) at group g
        #pragma unroll
        for (int nt = 0; nt < 2; ++nt) {
            float wr[4], wi[4];
            #pragma unroll
            for (int r = 0; r < 4; ++r) {
                const float zr = Zr[nt][r], zi = Zi[nt][r];
                const float s2  = fmaf(zr, zr, fmaf(zi, zi, 1e-24f));
                const float inv = __builtin_amdgcn_rsqf(s2);
                const float mag = s2 * inv;
                const float p   = __expf(mag - MBIAS);
                l_run += p;
                const float w = p * inv;
                wr[r] = w * zr; wi[r] = w * zi;
            }
            PkR[nt*2 + 0] = pk2(wr[0], wr[1]);
            PkR[nt*2 + 1] = pk2(wr[2], wr[3]);
            PkI[nt*2 + 0] = pk2(wi[0], wi[1]);
            PkI[nt*2 + 1] = pk2(wi[2], wi[3]);
        }

        // ---- in-register P transpose: A-fragment (q=m, t=8g..8g+7) per plane ----
        half8 apr = xpose4(PkR[0], PkR[1], PkR[2], PkR[3]);
        half8 api = xpose4(PkI[0], PkI[1], PkI[2], PkI[3]);
        half8 nai = -api;

        // ---- PV: O += P * V. Row nt*16+m lives at slot nt*16+phi(m);
        // ---- chunk key unchanged (g ^ (m&3)) -> routing identical to R1.
        #pragma unroll
        for (int nt = 0; nt < 4; ++nt) {
            const int vrb = (nt*16 + fm) * 32;
            const int vck = (g ^ (m & 3)) * 8;
            half8 bvr = *(const half8*)&Vrt[vrb + vck];
            half8 bvi = *(const half8*)&Vit[vrb + vck];
            Or[nt] = MFMA16(apr, bvr, Or[nt]);
            Or[nt] = MFMA16(nai, bvi, Or[nt]);
            Oi[nt] = MFMA16(apr, bvi, Oi[nt]);
            Oi[nt] = MFMA16(api, bvr, Oi[nt]);
        }
    };

    _Float16* const buf0 = sm;
    _Float16* const buf1 = sm + 4*2048;

    stage(0, buf0);
    for (int kt = 0; kt < 64; kt += 2) {
        __syncthreads();                    // drains loads into buf0; separates prior compute(buf1)
        stage(kt + 1, buf1);
        compute(buf0);
        __syncthreads();                    // drains loads into buf1; separates compute(buf0)
        if (kt < 62) stage(kt + 2, buf0);
        compute(buf1);
    }

    // ---- deferred l reduction: sum over the g-quad (each lane has 8 t's per tile) ----
    l_run += __shfl_xor(l_run, 16, 64);
    l_run += __shfl_xor(l_run, 32, 64);
    // lane quad {m,m+16,m+32,m+48} now holds l(q=m); gather l(q=4g+r) for output rows

    #pragma unroll
    for (int r = 0; r < 4; ++r) {
        const float linv = 1.0f / __shfl(l_run, 4*g + r, 64);
        const size_t o = base + (size_t)(q0 + wv*16 + 4*g + r) * D + m;
        #pragma unroll
        for (int nt = 0; nt < 4; ++nt) {
            out[o + nt*16]         = Or[nt][r] * linv;
            out[PLANE + o + nt*16] = Oi[nt][r] * linv;
        }
    }
}

// ---------------- fallback (ws too small): round-2 style, f32 inputs ----------------
constexpr int ST2 = 72;
__global__ __launch_bounds__(256, 2)
void cv_attn_mfma(const float* __restrict__ qr_g, const float* __restrict__ qi_g,
                  const float* __restrict__ kr_g, const float* __restrict__ ki_g,
                  const float* __restrict__ vr_g, const float* __restrict__ vi_g,
                  float* __restrict__ out)
{
    __shared__ __align__(16) _Float16 sm[4*64*ST2 + 4*2*16*ST2];
    _Float16* const Kr = sm;
    _Float16* const Ki = Kr + 64*ST2;
    _Float16* const Vr = Ki + 64*ST2;
    _Float16* const Vi = Vr + 64*ST2;
    _Float16* const Pb = Vi + 64*ST2;

    const int tid = (int)threadIdx.x, lane = tid & 63, wv = tid >> 6;
    const int g = lane >> 4, m = lane & 15;
    const int bh = (int)blockIdx.y;
    const int q0 = (int)blockIdx.x * QT;
    const size_t base = (size_t)bh * S * D;
    _Float16* const Pr = Pb + wv * (2*16*ST2);
    _Float16* const Pi = Pr + 16*ST2;
    const int lofs = m*ST2 + g*8;

    half8 aqr[2], aqi[2], aqin[2];
    {
        const size_t qoff = base + (size_t)(q0 + wv*16 + m) * D + g*8;
        #pragma unroll
        for (int kc = 0; kc < 2; ++kc) {
            float4 r0 = *(const float4*)(qr_g + qoff + kc*32);
            float4 r1 = *(const float4*)(qr_g + qoff + kc*32 + 4);
            float4 i0 = *(const float4*)(qi_g + qoff + kc*32);
            float4 i1 = *(const float4*)(qi_g + qoff + kc*32 + 4);
            half8 hr, hi;
            hr[0]=(_Float16)(r0.x*INV_T); hr[1]=(_Float16)(r0.y*INV_T);
            hr[2]=(_Float16)(r0.z*INV_T); hr[3]=(_Float16)(r0.w*INV_T);
            hr[4]=(_Float16)(r1.x*INV_T); hr[5]=(_Float16)(r1.y*INV_T);
            hr[6]=(_Float16)(r1.z*INV_T); hr[7]=(_Float16)(r1.w*INV_T);
            hi[0]=(_Float16)(i0.x*INV_T); hi[1]=(_Float16)(i0.y*INV_T);
            hi[2]=(_Float16)(i0.z*INV_T); hi[3]=(_Float16)(i0.w*INV_T);
            hi[4]=(_Float16)(i1.x*INV_T); hi[5]=(_Float16)(i1.y*INV_T);
            hi[6]=(_Float16)(i1.z*INV_T); hi[7]=(_Float16)(i1.w*INV_T);
            aqr[kc] = hr; aqi[kc] = hi; aqin[kc] = -hi;
        }
    }

    floatx4 Or[4], Oi[4];
    float m_run[4], l_run[4];
    #pragma unroll
    for (int r = 0; r < 4; ++r) { m_run[r] = -INFINITY; l_run[r] = 0.f; }
    #pragma unroll
    for (int nt = 0; nt < 4; ++nt) {
        Or[nt] = (floatx4){0.f,0.f,0.f,0.f};
        Oi[nt] = (floatx4){0.f,0.f,0.f,0.f};
    }

    for (int kt = 0; kt < S/64; ++kt) {
        const int k0 = kt * 64;
        __syncthreads();
        if (wv < 2) {
            const float* src = (wv == 0 ? kr_g : ki_g) + base + (size_t)k0 * D;
            _Float16* dst = (wv == 0 ? Kr : Ki);
            #pragma unroll
            for (int it = 0; it < 16; ++it) {
                const int e = it*64 + lane, t = e >> 4, c4 = (e & 15) * 4;
                float4 v = *(const float4*)(src + t*64 + c4);
                half4_t hh = {(_Float16)v.x, (_Float16)v.y, (_Float16)v.z, (_Float16)v.w};
                *(half4_t*)&dst[t*ST2 + c4] = hh;
            }
        } else {
            const float* src = (wv == 2 ? vr_g : vi_g) + base + (size_t)k0 * D;
            _Float16* dst = (wv == 2 ? Vr : Vi);
            #pragma unroll
            for (int t0 = 0; t0 < 64; t0 += 4) {
                float v0 = src[(t0+0)*64 + lane];
                float v1 = src[(t0+1)*64 + lane];
                float v2 = src[(t0+2)*64 + lane];
                float v3 = src[(t0+3)*64 + lane];
                half4_t hh = {(_Float16)v0, (_Float16)v1, (_Float16)v2, (_Float16)v3};
                *(half4_t*)&dst[lane*ST2 + t0] = hh;
            }
        }
        __syncthreads();

        floatx4 Zr[4], Zi[4];
        #pragma unroll
        for (int nt = 0; nt < 4; ++nt) {
            floatx4 zr = (floatx4){0.f,0.f,0.f,0.f};
            floatx4 zi = (floatx4){0.f,0.f,0.f,0.f};
            #pragma unroll
            for (int kc = 0; kc < 2; ++kc) {
                const int o = nt*16*ST2 + lofs + kc*32;
                half8 bkr = *(const half8*)&Kr[o];
                half8 bki = *(const half8*)&Ki[o];
                zr = MFMA16(aqr[kc],  bkr, zr);
                zr = MFMA16(aqin[kc], bki, zr);
                zi = MFMA16(aqr[kc],  bki, zi);
                zi = MFMA16(aqi[kc],  bkr, zi);
            }
            Zr[nt] = zr; Zi[nt] = zi;
        }

        float mag[4][4], mt[4] = {0.f,0.f,0.f,0.f};
        #pragma unroll
        for (int nt = 0; nt < 4; ++nt)
            #pragma unroll
            for (int r = 0; r < 4; ++r) {
                const float a = Zr[nt][r], bz = Zi[nt][r];
                const float s = __builtin_amdgcn_sqrtf(a*a + bz*bz);
                mag[nt][r] = s; mt[r] = fmaxf(mt[r], s);
            }
        #pragma unroll
        for (int off = 1; off < 16; off <<= 1)
            #pragma unroll
            for (int r = 0; r < 4; ++r)
                mt[r] = fmaxf(mt[r], __shfl_xor(mt[r], off, 64));

        float alpha[4], rs[4];
        #pragma unroll
        for (int r = 0; r < 4; ++r) {
            const float mnew = fmaxf(m_run[r], mt[r]);
            alpha[r] = __expf(m_run[r] - mnew);
            m_run[r] = mnew; rs[r] = 0.f;
        }
        #pragma unroll
        for (int nt = 0; nt < 4; ++nt)
            #pragma unroll
            for (int r = 0; r < 4; ++r) {
                const float p = __expf(mag[nt][r] - m_run[r]);
                rs[r] += p;
                const float w = p * __builtin_amdgcn_rcpf(fmaxf(mag[nt][r], 1e-12f));
                Pr[(4*g + r)*ST2 + nt*16 + m] = (_Float16)(w * Zr[nt][r]);
                Pi[(4*g + r)*ST2 + nt*16 + m] = (_Float16)(w * Zi[nt][r]);
            }
        #pragma unroll
        for (int off = 1; off < 16; off <<= 1)
            #pragma unroll
            for (int r = 0; r < 4; ++r)
                rs[r] += __shfl_xor(rs[r], off, 64);
        #pragma unroll
        for (int r = 0; r < 4; ++r) l_run[r] = l_run[r]*alpha[r] + rs[r];

        #pragma unroll
        for (int nt = 0; nt < 4; ++nt)
            #pragma unroll
            for (int r = 0; r < 4; ++r) { Or[nt][r] *= alpha[r]; Oi[nt][r] *= alpha[r]; }

        half8 apr[2], api[2], apin[2];
        #pragma unroll
        for (int kc = 0; kc < 2; ++kc) {
            apr[kc]  = *(const half8*)&Pr[lofs + kc*32];
            api[kc]  = *(const half8*)&Pi[lofs + kc*32];
            apin[kc] = -api[kc];
        }
        #pragma unroll
        for (int nt = 0; nt < 4; ++nt) {
            floatx4 ors = Or[nt], ois = Oi[nt];
            #pragma unroll
            for (int kc = 0; kc < 2; ++kc) {
                const int o = nt*16*ST2 + lofs + kc*32;
                half8 bvr = *(const half8*)&Vr[o];
                half8 bvi = *(const half8*)&Vi[o];
                ors = MFMA16(apr[kc],  bvr, ors);
                ors = MFMA16(apin[kc], bvi, ors);
                ois = MFMA16(apr[kc],  bvi, ois);
                ois = MFMA16(api[kc],  bvr, ois);
            }
            Or[nt] = ors; Oi[nt] = ois;
        }
    }

    #pragma unroll
    for (int r = 0; r < 4; ++r) {
        const float linv = 1.0f / l_run[r];
        const size_t o = base + (size_t)(q0 + wv*16 + 4*g + r) * D + m;
        #pragma unroll
        for (int nt = 0; nt < 4; ++nt) {
            out[o + nt*16]         = Or[nt][r] * linv;
            out[PLANE + o + nt*16] = Oi[nt][r] * linv;
        }
    }
}

} // namespace

extern "C" void kernel_launch(void* const* d_in, const int* in_sizes, int n_in,
                              void* d_out, int out_size, void* d_ws, size_t ws_size,
                              hipStream_t stream) {
    const float* qr = (const float*)d_in[0];
    const float* qi = (const float*)d_in[1];
    const float* kr = (const float*)d_in[2];
    const float* ki = (const float*)d_in[3];
    const float* vr = (const float*)d_in[4];
    const float* vi = (const float*)d_in[5];
    float* out = (float*)d_out;

    const size_t PH = (size_t)BH * S * D;            // halves per ws plane
    const size_t need = 4 * PH * sizeof(_Float16);   // 33.6 MB
    if (ws_size >= need) {
        _Float16* khr = (_Float16*)d_ws;
        _Float16* khi = khr + PH;
        _Float16* vtr = khi + PH;
        _Float16* vti = vtr + PH;
        prep_all<<<dim3(32, 32, 4), 256, 0, stream>>>(kr, ki, vr, vi, khr, khi, vtr, vti);
        cv_attn_db<<<1024, 256, 0, stream>>>(qr, qi, khr, khi, vtr, vti, out);
    } else {
        cv_attn_mfma<<<dim3(32, 32), 256, 0, stream>>>(qr, qi, kr, ki, vr, vi, out);
    }
}